// Round 8
// baseline (716.247 us; speedup 1.0000x reference)
//
#include <hip/hip_runtime.h>
#include <math.h>

// Instant-NGP hash grid encoder, MI355X. Round 8: corner-pair fused loads.
//
// Round-7 A/B: 2x per-thread MLP -> no gain => gather is NOT latency-bound;
// it's per-address/line throughput-bound. This round cuts address events:
// for each (cy,cz), x-corner indices are idx_lo=(ix^q)&M, idx_hi=((ix+1)^q)&M.
// Even ix => idx_hi = idx_lo^1 = adjacent entry => ONE aligned b128 pair
// load covers both corners. Odd-ix lanes issue one extra exec-masked b64.
// 8 gather instrs/pt -> 4 + ~2 masked (-37% instrs, -25% TA addresses),
// identical bytes on even lanes, unchanged L2 line count.
//  - gather sum drops ~25% => TA/L1-address-rate-bound confirmed.
//  - unchanged => L2-line-path-bound; pivot to scratch-traffic removal.

#define LEVELS 16
#define LOG2_T 19
#define TMASK ((1u << LOG2_T) - 1u)

typedef float f32x2 __attribute__((ext_vector_type(2)));
typedef float f32x4 __attribute__((ext_vector_type(4)));

struct ResArgs { float r[LEVELS]; };

// Corner-pair-load encode. Bit-exact same arithmetic as the reference:
// identical hash indices, identical fp32 weight/fma chain.
__device__ __forceinline__ f32x2 encode_one_pl(
    const f32x2* __restrict__ tbl, float rf,
    float x0, float x1, float x2)
{
    const float sx = x0 * rf, sy = x1 * rf, sz = x2 * rf;
    const float px = floorf(sx), py = floorf(sy), pz = floorf(sz);
    const float fx = sx - px, fy = sy - py, fz = sz - pz;
    const unsigned ix = (unsigned)px, iy = (unsigned)py, iz = (unsigned)pz;

    const unsigned hy0 = iy * 2654435761u;
    const unsigned hy1 = hy0 + 2654435761u;
    const unsigned hz0 = iz * 805459861u;
    const unsigned hz1 = hz0 + 805459861u;

    const unsigned q00 = hy0 ^ hz0;
    const unsigned q10 = hy1 ^ hz0;
    const unsigned q01 = hy0 ^ hz1;
    const unsigned q11 = hy1 ^ hz1;

    const unsigned i00 = (ix ^ q00) & TMASK;   // low-x corner indices
    const unsigned i10 = (ix ^ q10) & TMASK;
    const unsigned i01 = (ix ^ q01) & TMASK;
    const unsigned i11 = (ix ^ q11) & TMASK;

    // Aligned pair loads: entries {i&~1, i|1} in one 16 B b128.
    const f32x4 P00 = *(const f32x4*)&tbl[i00 & ~1u];
    const f32x4 P10 = *(const f32x4*)&tbl[i10 & ~1u];
    const f32x4 P01 = *(const f32x4*)&tbl[i01 & ~1u];
    const f32x4 P11 = *(const f32x4*)&tbl[i11 & ~1u];

    // Select low corner and its in-pair partner (= entry i^1).
    f32x2 lo00, lo10, lo01, lo11, hi00, hi10, hi01, hi11;
    {
        const bool b0 = (i00 & 1u);
        lo00.x = b0 ? P00.z : P00.x; lo00.y = b0 ? P00.w : P00.y;
        hi00.x = b0 ? P00.x : P00.z; hi00.y = b0 ? P00.y : P00.w;
        const bool b1 = (i10 & 1u);
        lo10.x = b1 ? P10.z : P10.x; lo10.y = b1 ? P10.w : P10.y;
        hi10.x = b1 ? P10.x : P10.z; hi10.y = b1 ? P10.y : P10.w;
        const bool b2 = (i01 & 1u);
        lo01.x = b2 ? P01.z : P01.x; lo01.y = b2 ? P01.w : P01.y;
        hi01.x = b2 ? P01.x : P01.z; hi01.y = b2 ? P01.y : P01.w;
        const bool b3 = (i11 & 1u);
        lo11.x = b3 ? P11.z : P11.x; lo11.y = b3 ? P11.w : P11.y;
        hi11.x = b3 ? P11.x : P11.z; hi11.y = b3 ? P11.y : P11.w;
    }

    // Even ix: partner IS the high-x corner (idx_hi = idx_lo^1).
    // Odd ix: fetch the 4 true high-x corners (exec-masked half-wave).
    if (ix & 1u) {
        const unsigned ixp = ix + 1u;
        hi00 = tbl[(ixp ^ q00) & TMASK];
        hi10 = tbl[(ixp ^ q10) & TMASK];
        hi01 = tbl[(ixp ^ q01) & TMASK];
        hi11 = tbl[(ixp ^ q11) & TMASK];
    }

    const float wx1 = fx, wx0 = 1.0f - fx;
    const float wy1 = fy, wy0 = 1.0f - fy;
    const float wz1 = fz, wz0 = 1.0f - fz;
    const float w00 = wy0 * wz0;
    const float w10 = wy1 * wz0;
    const float w01 = wy0 * wz1;
    const float w11 = wy1 * wz1;

    float w, a0, a1;
    w = wx0 * w00; a0 = w * lo00.x;          a1 = w * lo00.y;
    w = wx1 * w00; a0 = fmaf(w, hi00.x, a0); a1 = fmaf(w, hi00.y, a1);
    w = wx0 * w10; a0 = fmaf(w, lo10.x, a0); a1 = fmaf(w, lo10.y, a1);
    w = wx1 * w10; a0 = fmaf(w, hi10.x, a0); a1 = fmaf(w, hi10.y, a1);
    w = wx0 * w01; a0 = fmaf(w, lo01.x, a0); a1 = fmaf(w, lo01.y, a1);
    w = wx1 * w01; a0 = fmaf(w, hi01.x, a0); a1 = fmaf(w, hi01.y, a1);
    w = wx0 * w11; a0 = fmaf(w, lo11.x, a0); a1 = fmaf(w, lo11.y, a1);
    w = wx1 * w11; a0 = fmaf(w, hi11.x, a0); a1 = fmaf(w, hi11.y, a1);

    f32x2 o; o.x = a0; o.y = a1;
    return o;
}

// Plain 8-load encode (fallback path keeps the proven round-3 form).
__device__ __forceinline__ f32x2 encode_one(
    const f32x2* __restrict__ tbl, float rf,
    float x0, float x1, float x2)
{
    const float sx = x0 * rf, sy = x1 * rf, sz = x2 * rf;
    const float px = floorf(sx), py = floorf(sy), pz = floorf(sz);
    const float fx = sx - px, fy = sy - py, fz = sz - pz;
    const unsigned ix = (unsigned)px, iy = (unsigned)py, iz = (unsigned)pz;
    const unsigned hx0 = ix, hx1 = ix + 1u;
    const unsigned hy0 = iy * 2654435761u, hy1 = hy0 + 2654435761u;
    const unsigned hz0 = iz * 805459861u,  hz1 = hz0 + 805459861u;
    const f32x2 c000 = tbl[(hx0 ^ hy0 ^ hz0) & TMASK];
    const f32x2 c100 = tbl[(hx1 ^ hy0 ^ hz0) & TMASK];
    const f32x2 c010 = tbl[(hx0 ^ hy1 ^ hz0) & TMASK];
    const f32x2 c110 = tbl[(hx1 ^ hy1 ^ hz0) & TMASK];
    const f32x2 c001 = tbl[(hx0 ^ hy0 ^ hz1) & TMASK];
    const f32x2 c101 = tbl[(hx1 ^ hy0 ^ hz1) & TMASK];
    const f32x2 c011 = tbl[(hx0 ^ hy1 ^ hz1) & TMASK];
    const f32x2 c111 = tbl[(hx1 ^ hy1 ^ hz1) & TMASK];
    const float wx1 = fx, wx0 = 1.0f - fx;
    const float wy1 = fy, wy0 = 1.0f - fy;
    const float wz1 = fz, wz0 = 1.0f - fz;
    const float w00 = wy0 * wz0, w10 = wy1 * wz0;
    const float w01 = wy0 * wz1, w11 = wy1 * wz1;
    float w, a0, a1;
    w = wx0 * w00; a0 = w * c000.x;          a1 = w * c000.y;
    w = wx1 * w00; a0 = fmaf(w, c100.x, a0); a1 = fmaf(w, c100.y, a1);
    w = wx0 * w10; a0 = fmaf(w, c010.x, a0); a1 = fmaf(w, c010.y, a1);
    w = wx1 * w10; a0 = fmaf(w, c110.x, a0); a1 = fmaf(w, c110.y, a1);
    w = wx0 * w01; a0 = fmaf(w, c001.x, a0); a1 = fmaf(w, c001.y, a1);
    w = wx1 * w01; a0 = fmaf(w, c101.x, a0); a1 = fmaf(w, c101.y, a1);
    w = wx0 * w11; a0 = fmaf(w, c011.x, a0); a1 = fmaf(w, c011.y, a1);
    w = wx1 * w11; a0 = fmaf(w, c111.x, a0); a1 = fmaf(w, c111.y, a1);
    f32x2 o; o.x = a0; o.y = a1;
    return o;
}

// ---- Per-level gather (1 pt/thread, round-6 shape + pair loads) ---------
__global__ __launch_bounds__(256) void ngp_gather_level(
    const float* __restrict__ x,
    const float* __restrict__ table,
    f32x2* __restrict__ out_t,     // [LEVELS][n] scratch
    float rf, int level, unsigned n)
{
    const unsigned p = blockIdx.x * 256u + threadIdx.x;
    if (p >= n) return;
    const float x0 = __builtin_nontemporal_load(&x[3u*p]);
    const float x1 = __builtin_nontemporal_load(&x[3u*p+1u]);
    const float x2 = __builtin_nontemporal_load(&x[3u*p+2u]);
    const f32x2* __restrict__ tbl =
        (const f32x2*)table + ((size_t)level << LOG2_T);
    f32x2 o = encode_one_pl(tbl, rf, x0, x1, x2);
    // wave-contiguous 512 B per instruction -> nt safe.
    __builtin_nontemporal_store(o, &out_t[(size_t)level * n + p]);
}

// ---- LDS transpose (round-7, UNCHANGED: control for the A/B) ------------
__global__ __launch_bounds__(256) void ngp_transpose_lds(
    const f32x2* __restrict__ out_t,
    f32x4* __restrict__ out,       // [n*8] f32x4
    unsigned n)                    // host guarantees n % 256 == 0
{
    __shared__ f32x2 lds[128][LEVELS + 1];
    const unsigned t = threadIdx.x;
    const unsigned pbase = blockIdx.x * 256u;

    #pragma unroll
    for (int half = 0; half < 2; ++half) {
        const unsigned p0 = pbase + (unsigned)half * 128u;
        #pragma unroll
        for (int j = 0; j < 8; ++j) {
            const unsigned idx = (unsigned)j * 256u + t;
            const unsigned l  = idx >> 7;
            const unsigned pp = idx & 127u;
            lds[pp][l] = out_t[(size_t)l * n + p0 + pp];
        }
        __syncthreads();
        #pragma unroll
        for (int j = 0; j < 4; ++j) {
            const unsigned g = (unsigned)j * 256u + t;
            const unsigned p = g >> 3, q = g & 7u;
            const f32x2 a = lds[p][2u*q];
            const f32x2 b = lds[p][2u*q + 1u];
            f32x4 v; v.x = a.x; v.y = a.y; v.z = b.x; v.w = b.y;
            __builtin_nontemporal_store(v, &out[(size_t)p0 * 8u + g]);
        }
        __syncthreads();
    }
}

// ---- Fallback (round-3 proven): direct point-major ----------------------
__global__ __launch_bounds__(256) void ngp_encode_direct(
    const float* __restrict__ x,
    const float* __restrict__ table,
    f32x2* __restrict__ out,
    ResArgs res,
    unsigned n_points)
{
    const unsigned t = blockIdx.x * 256u + threadIdx.x;
    const unsigned level = t & (LEVELS - 1u);
    const unsigned p = t >> 4;
    if (p >= n_points) return;
    const float x0 = x[3u*p], x1 = x[3u*p+1u], x2 = x[3u*p+2u];
    const f32x2* __restrict__ tbl =
        (const f32x2*)table + ((size_t)level << LOG2_T);
    f32x2 o = encode_one(tbl, res.r[level], x0, x1, x2);
    __builtin_nontemporal_store(o, &out[t]);
}

extern "C" void kernel_launch(void* const* d_in, const int* in_sizes, int n_in,
                              void* d_out, int out_size, void* d_ws, size_t ws_size,
                              hipStream_t stream) {
    const float* x     = (const float*)d_in[0];
    const float* table = (const float*)d_in[1];
    const unsigned n_points = (unsigned)(in_sizes[0] / 3);

    // numpy RES replication (same host libm).
    ResArgs res;
    const double scale = exp((log(512.0) - log(16.0)) / 15.0);
    for (int l = 0; l < LEVELS; ++l) {
        res.r[l] = (float)floor(16.0 * pow(scale, (double)l));
    }

    const size_t scratch_needed = (size_t)LEVELS * n_points * sizeof(f32x2);
    const bool fits = (ws_size >= scratch_needed) && (n_points % 256u == 0u);

    if (fits) {
        f32x2* out_t = (f32x2*)d_ws;
        const unsigned nblk = n_points / 256u;
        for (int l = 0; l < LEVELS; ++l) {
            ngp_gather_level<<<dim3(nblk), dim3(256), 0, stream>>>(
                x, table, out_t, res.r[l], l, n_points);
        }
        ngp_transpose_lds<<<dim3(nblk), dim3(256), 0, stream>>>(
            out_t, (f32x4*)d_out, n_points);
    } else {
        const unsigned total = n_points * LEVELS;
        const unsigned nblk = (total + 255u) / 256u;
        ngp_encode_direct<<<dim3(nblk), dim3(256), 0, stream>>>(
            x, table, (f32x2*)d_out, res, n_points);
    }
}